// Round 5
// baseline (259.831 us; speedup 1.0000x reference)
//
#include <hip/hip_runtime.h>

#define B_   32
#define S_   2048
#define D_   512
#define H_   32
#define BS_  (B_*S_)
#define NTILE_ (BS_/32)          // 2048 tiles of 32 rows
#define TPB_   2                 // tiles per block (pipelined)
#define GRID_  (NTILE_/TPB_)     // 1024 blocks ~= 3 resident/CU (LDS-limited)
#define INV_SCALE 0.17677669529663689f   // 1/sqrt(32)

// workspace layout (bytes):
// [0, 32768):            PTbf    ushort[32][512]   bf16 transposed projector
// [32768, 49152):        zdm     float2[2048]      per-tile (Z, DM) partials
// [49152, 4243456):      partial float[2048][512]  per-tile numerator partials

typedef short  s16x8 __attribute__((ext_vector_type(8)));
typedef float  f32x4 __attribute__((ext_vector_type(4)));

__device__ __forceinline__ float sigmoidf_(float x) {
    return 1.0f / (1.0f + __expf(-x));
}

__device__ __forceinline__ unsigned short f2bf(float f) {
    unsigned u = __float_as_uint(f);
    u += 0x7fffu + ((u >> 16) & 1u);     // round-to-nearest-even
    return (unsigned short)(u >> 16);
}

// LDS-ordering barrier that does NOT drain vmcnt: register-destined global
// prefetch loads stay in flight across it; the compiler's dataflow inserts
// incremental vmcnt(N) waits at first use of each prefetched value.
__device__ __forceinline__ void barrier_lds() {
    asm volatile("s_waitcnt lgkmcnt(0)" ::: "memory");
    __builtin_amdgcn_s_barrier();
    asm volatile("" ::: "memory");
}

// ---------------- transpose projector to bf16: PTbf[j][d] = bf16(P[d][j]) ----
__global__ void kTransposeBf(const float* __restrict__ P, unsigned short* __restrict__ PTbf) {
    int o = blockIdx.x * 256 + threadIdx.x;      // 16384 total
    int j = o >> 9, d = o & 511;
    PTbf[o] = f2bf(P[d * H_ + j]);
}

// ---- fused scores + unnormalized weighted partial sum ----
#define XST 520                               // bf16 row stride in LDS (512 + 8 pad)
#define WST 36                                // w0f row stride (floats), 16B rows

__global__ __launch_bounds__(256, 3) void kFused(
        const float* __restrict__ inp, const int* __restrict__ mask,
        const unsigned short* __restrict__ PTbf, const float* __restrict__ hd,
        const float* __restrict__ ev,
        float* __restrict__ partial, float2* __restrict__ zdm) {
    __shared__ __align__(16) unsigned short xs[32 * XST];   // 33280 B
    __shared__ __align__(16) float w0f[32 * WST];           // 4608 B
    __shared__ __align__(16) float hds[32 * 32];            // 4096 B hidden matrix
    __shared__ float cs[32];                  // m * exp(v)
    __shared__ float es[32];                  // exp(v)
    __shared__ float mskAll[TPB_ * 32];       // masks for both tiles

    const int tid = threadIdx.x;
    const int wave = tid >> 6, lane = tid & 63;
    const int rt = wave & 1, ct = wave >> 1;
    const int m = lane & 15, quad = lane >> 4;
    const int tile0 = blockIdx.x * TPB_;

    // ---- issue tile-0 loads FIRST so HBM starts immediately ----
    float4 tmp[16];                                    // 64 VGPR
    {
        const float4* g = (const float4*)inp + (size_t)tile0 * 4096;
        #pragma unroll
        for (int i = 0; i < 16; ++i)
            tmp[i] = g[i * 256 + tid];                 // flat index == row*128 + kq
    }

    // ---- per-block persistent state ----
    s16x8 bf[16];                                      // 64 VGPR (B fragments)
    {
        const unsigned short* brow = PTbf + (size_t)(ct * 16 + m) * 512 + quad * 8;
        #pragma unroll
        for (int ks = 0; ks < 16; ++ks)
            bf[ks] = *(const s16x8*)(brow + ks * 32);
    }
    const int k = tid & 31, slot = tid >> 5;
    ((float4*)hds)[tid] = ((const float4*)hd)[tid];    // 4 KiB stage (exactly 256 f4)
    const float evk = ev[k];
    if (tid < TPB_ * 32)
        mskAll[tid] = (mask[tile0 * 32 + tid] != 0) ? 1.0f : 0.0f;

    for (int t = 0; t < TPB_; ++t) {
        const int tile = tile0 + t;

        // ---- stage tile t: bf16 convert + LDS write (incremental vmcnt waits) ----
        #pragma unroll
        for (int i = 0; i < 16; ++i) {
            int fi = i * 256 + tid;
            int row = fi >> 7, kq = fi & 127;
            unsigned p0, p1;                  // HW RNE pack
            asm("v_cvt_pk_bf16_f32 %0, %1, %2" : "=v"(p0) : "v"(tmp[i].x), "v"(tmp[i].y));
            asm("v_cvt_pk_bf16_f32 %0, %1, %2" : "=v"(p1) : "v"(tmp[i].z), "v"(tmp[i].w));
            uint2 u; u.x = p0; u.y = p1;
            *(uint2*)(xs + row * XST + kq * 4) = u;
        }
        barrier_lds();                                  // (1) xs/hds/msk ready

        // ---- prefetch tile t+1: stays in flight across ALL tail barriers ----
        if (t + 1 < TPB_) {
            const float4* g2 = (const float4*)inp + (size_t)(tile + 1) * 4096;
            #pragma unroll
            for (int i = 0; i < 16; ++i)
                tmp[i] = g2[i * 256 + tid];
        }

        // ---- MFMA: each wave one 16x16 tile (rowtile rt, coltile ct) ----
        const unsigned short* arow = xs + (rt * 16 + m) * XST + quad * 8;
        f32x4 acc = {0.f, 0.f, 0.f, 0.f};
        #pragma unroll
        for (int ks = 0; ks < 16; ++ks) {
            s16x8 a = *(const s16x8*)(arow + ks * 32);
            acc = __builtin_amdgcn_mfma_f32_16x16x32_bf16(a, bf[ks], acc, 0, 0, 0);
        }

        // epilogue: sigmoid(mask * score / sqrt(32)) -> w0f
        // C/D layout: col = lane&15, row = quad*4 + reg
        #pragma unroll
        for (int r = 0; r < 4; ++r) {
            int rowL = rt * 16 + quad * 4 + r;
            w0f[rowL * WST + ct * 16 + m] =
                sigmoidf_(mskAll[t * 32 + rowL] * acc[r] * INV_SCALE);
        }
        barrier_lds();                                  // (2) w0f ready

        // ---- hidden layer + evaluator fused, all 256 threads busy ----
        #pragma unroll
        for (int tt = 0; tt < 4; ++tt) {
            const int row = slot + 8 * tt;
            const float4* wr = (const float4*)(w0f + row * WST); // broadcast reads
            float s = 0.f;
            #pragma unroll
            for (int i = 0; i < 8; ++i) {
                float4 w4 = wr[i];
                s = fmaf(w4.x, hds[(4 * i + 0) * 32 + k], s);   // conflict-free LDS
                s = fmaf(w4.y, hds[(4 * i + 1) * 32 + k], s);
                s = fmaf(w4.z, hds[(4 * i + 2) * 32 + k], s);
                s = fmaf(w4.w, hds[(4 * i + 3) * 32 + k], s);
            }
            float val = sigmoidf_(s * INV_SCALE) * evk;   // w1[row][k] * ev[k]
            #pragma unroll
            for (int o = 1; o < 32; o <<= 1)              // sum over k (32-lane group)
                val += __shfl_xor(val, o);
            if (k == 0) {
                float v2 = sigmoidf_(val * INV_SCALE);    // in (0,1): exp safe
                float e  = __expf(v2);
                es[row] = e;
                cs[row] = mskAll[t * 32 + row] * e;
            }
        }
        barrier_lds();                                  // (3) cs/es ready

        // ---- tile (Z, DM) partial: wave 0 only ----
        if (tid < 64) {
            float z = 0.f, dm = 0.f;
            if (tid < 32) { z = es[tid]; dm = cs[tid]; }
            #pragma unroll
            for (int o = 32; o > 0; o >>= 1) {
                z  += __shfl_down(z, o);
                dm += __shfl_down(dm, o);
            }
            if (tid == 0) zdm[tile] = make_float2(z, dm);
        }

        // ---- numerator partial: thread owns d = {2*tid, 2*tid+1} ----
        float a0 = 0.f, a1 = 0.f;
        #pragma unroll 8
        for (int row = 0; row < 32; ++row) {
            unsigned u = *(const unsigned*)(xs + row * XST + 2 * tid); // conflict-free
            float x0 = __uint_as_float(u << 16);           // element 2*tid
            float x1 = __uint_as_float(u & 0xffff0000u);   // element 2*tid+1
            float c = cs[row];                              // broadcast
            a0 = fmaf(c, x0, a0);
            a1 = fmaf(c, x1, a1);
        }
        ((float2*)(partial + (size_t)tile * 512))[tid] = make_float2(a0, a1);

        barrier_lds();                                  // (4) xs reads done
    }
}

// ---- reduce 64 partials per b, normalize, write out ----
// grid = 32 batches x 8 column-chunks = 256 blocks (all CUs busy).
// Each thread sums 8 tiles for one float2 column (8 loads in flight),
// then an LDS combine across the 8 tile-groups.
__global__ __launch_bounds__(256) void kReduce(
        const float* __restrict__ partial, const float2* __restrict__ zdm,
        float* __restrict__ out) {
    const int b = blockIdx.x >> 3, chunk = blockIdx.x & 7;
    const int tid = threadIdx.x;
    const int c  = tid & 31;             // column within chunk
    const int g  = tid >> 5;             // tile-group 0..7
    const int d2 = chunk * 32 + c;       // float2 column 0..255
    __shared__ float sInv;
    __shared__ float2 red[7][32];

    if (tid < 64) {                      // redundant per block: 512 B from L2
        float2 p = zdm[b * 64 + tid];
        float z = p.x, dm = p.y;
        #pragma unroll
        for (int o = 32; o > 0; o >>= 1) {
            z  += __shfl_down(z, o);
            dm += __shfl_down(dm, o);
        }
        if (tid == 0) sInv = 1.0f / (dm + 1e-12f * z);
    }

    const float2* pp = (const float2*)partial + (size_t)b * 64 * 256 + d2;
    float2 v[8];
    #pragma unroll
    for (int j = 0; j < 8; ++j)                       // 8 loads in flight
        v[j] = pp[(size_t)(g * 8 + j) * 256];
    float a = 0.f, cc = 0.f;
    #pragma unroll
    for (int j = 0; j < 8; ++j) { a += v[j].x; cc += v[j].y; }

    if (g) red[g - 1][c] = make_float2(a, cc);
    __syncthreads();
    if (g == 0) {
        #pragma unroll
        for (int q = 0; q < 7; ++q) { a += red[q][c].x; cc += red[q][c].y; }
        const float inv = sInv;
        ((float2*)out)[b * 256 + d2] = make_float2(a * inv, cc * inv);
    }
}

extern "C" void kernel_launch(void* const* d_in, const int* in_sizes, int n_in,
                              void* d_out, int out_size, void* d_ws, size_t ws_size,
                              hipStream_t stream) {
    const float* inp  = (const float*)d_in[0];
    const int*   mask = (const int*)d_in[1];
    const float* proj = (const float*)d_in[2];
    const float* hid  = (const float*)d_in[3];   // [1][32][32]
    const float* ev   = (const float*)d_in[4];   // [32]
    float* out = (float*)d_out;

    unsigned short* PTbf = (unsigned short*)d_ws;
    float2* zdm     = (float2*)((char*)d_ws + 32768);
    float*  partial = (float*)((char*)d_ws + 49152);

    kTransposeBf<<<64, 256, 0, stream>>>(proj, PTbf);
    kFused      <<<GRID_, 256, 0, stream>>>(inp, mask, PTbf, hid, ev, partial, zdm);
    kReduce     <<<B_ * 8, 256, 0, stream>>>(partial, zdm, out);
}

// Round 6
// 209.232 us; speedup vs baseline: 1.2418x; 1.2418x over previous
//
#include <hip/hip_runtime.h>

#define B_   32
#define S_   2048
#define D_   512
#define H_   32
#define BS_  (B_*S_)
#define NTILE_ (BS_/32)          // 2048 tiles of 32 rows
#define TPB_   4                 // tiles per block (pipelined)
#define GRID_  (NTILE_/TPB_)     // 512 blocks = 2 per CU
#define INV_SCALE 0.17677669529663689f   // 1/sqrt(32)

// workspace layout (bytes):
// [0, 32768):            PTbf    ushort[32][512]   bf16 transposed projector
// [32768, 49152):        zdm     float2[2048]      per-tile (Z, DM) partials
// [49152, 4243456):      partial float[2048][512]  per-tile numerator partials

typedef short  s16x8 __attribute__((ext_vector_type(8)));
typedef float  f32x4 __attribute__((ext_vector_type(4)));

__device__ __forceinline__ float sigmoidf_(float x) {
    return 1.0f / (1.0f + __expf(-x));
}

__device__ __forceinline__ unsigned short f2bf(float f) {
    unsigned u = __float_as_uint(f);
    u += 0x7fffu + ((u >> 16) & 1u);     // round-to-nearest-even
    return (unsigned short)(u >> 16);
}

// LDS-ordering barrier that does NOT drain vmcnt: register-destined global
// prefetch loads stay in flight across it; the compiler's dataflow inserts
// incremental vmcnt(N) waits at first use of each prefetched value.
__device__ __forceinline__ void barrier_lds() {
    asm volatile("s_waitcnt lgkmcnt(0)" ::: "memory");
    __builtin_amdgcn_s_barrier();
    asm volatile("" ::: "memory");
}

// ---------------- transpose projector to bf16: PTbf[j][d] = bf16(P[d][j]) ----
__global__ void kTransposeBf(const float* __restrict__ P, unsigned short* __restrict__ PTbf) {
    int o = blockIdx.x * 256 + threadIdx.x;      // 16384 total
    int j = o >> 9, d = o & 511;
    PTbf[o] = f2bf(P[d * H_ + j]);
}

// ---- fused scores + unnormalized weighted partial sum ----
#define XST 520                               // bf16 row stride in LDS (512 + 8 pad)
#define WST 36                                // w0f row stride (floats), 16B rows

// __launch_bounds__(256,2): VGPR cap 256. The kernel holds ~170 live regs
// (tmp[16]=64, bf[16]=64, working ~40). R5 showed that forcing 3 waves/EU
// (cap 170 -> allocator chose 84) spills tmp to scratch: WRITE_SIZE blew up
// 4.3MB -> 82MB and kFused ran 119us at 0.7% MfmaUtil. Do not raise this.
__global__ __launch_bounds__(256, 2) void kFused(
        const float* __restrict__ inp, const int* __restrict__ mask,
        const unsigned short* __restrict__ PTbf, const float* __restrict__ hd,
        const float* __restrict__ ev,
        float* __restrict__ partial, float2* __restrict__ zdm) {
    __shared__ __align__(16) unsigned short xs[32 * XST];   // 33280 B
    __shared__ __align__(16) float w0f[32 * WST];           // 4608 B
    __shared__ __align__(16) float hds[32 * 32];            // 4096 B hidden matrix
    __shared__ float cs[32];                  // m * exp(v)
    __shared__ float es[32];                  // exp(v)
    __shared__ float mskAll[TPB_ * 32];       // masks for all 4 tiles

    const int tid = threadIdx.x;
    const int wave = tid >> 6, lane = tid & 63;
    const int rt = wave & 1, ct = wave >> 1;
    const int m = lane & 15, quad = lane >> 4;
    const int tile0 = blockIdx.x * TPB_;

    // ---- issue tile-0 loads FIRST so HBM starts immediately ----
    float4 tmp[16];                                    // 64 VGPR
    {
        const float4* g = (const float4*)inp + (size_t)tile0 * 4096;
        #pragma unroll
        for (int i = 0; i < 16; ++i)
            tmp[i] = g[i * 256 + tid];                 // flat index == row*128 + kq
    }

    // ---- per-block persistent state ----
    s16x8 bf[16];                                      // 64 VGPR (B fragments)
    {
        const unsigned short* brow = PTbf + (size_t)(ct * 16 + m) * 512 + quad * 8;
        #pragma unroll
        for (int ks = 0; ks < 16; ++ks)
            bf[ks] = *(const s16x8*)(brow + ks * 32);
    }
    const int k = tid & 31, slot = tid >> 5;
    ((float4*)hds)[tid] = ((const float4*)hd)[tid];    // 4 KiB stage (exactly 256 f4)
    const float evk = ev[k];
    if (tid < TPB_ * 32)
        mskAll[tid] = (mask[tile0 * 32 + tid] != 0) ? 1.0f : 0.0f;

    for (int t = 0; t < TPB_; ++t) {
        const int tile = tile0 + t;

        // ---- stage tile t: bf16 convert + LDS write (incremental vmcnt waits) ----
        #pragma unroll
        for (int i = 0; i < 16; ++i) {
            int fi = i * 256 + tid;
            int row = fi >> 7, kq = fi & 127;
            unsigned p0, p1;                  // HW RNE pack
            asm("v_cvt_pk_bf16_f32 %0, %1, %2" : "=v"(p0) : "v"(tmp[i].x), "v"(tmp[i].y));
            asm("v_cvt_pk_bf16_f32 %0, %1, %2" : "=v"(p1) : "v"(tmp[i].z), "v"(tmp[i].w));
            uint2 u; u.x = p0; u.y = p1;
            *(uint2*)(xs + row * XST + kq * 4) = u;
        }

        // ---- prefetch tile t+1 BEFORE the barrier (tmp is dead after cvt):
        // loads start during other waves' cvt and stay in flight across all
        // tail barriers (barrier_lds never drains vmcnt).
        if (t + 1 < TPB_) {
            const float4* g2 = (const float4*)inp + (size_t)(tile + 1) * 4096;
            #pragma unroll
            for (int i = 0; i < 16; ++i)
                tmp[i] = g2[i * 256 + tid];
        }
        barrier_lds();                                  // (1) xs/hds/msk ready

        // ---- MFMA: each wave one 16x16 tile (rowtile rt, coltile ct) ----
        const unsigned short* arow = xs + (rt * 16 + m) * XST + quad * 8;
        f32x4 acc = {0.f, 0.f, 0.f, 0.f};
        #pragma unroll
        for (int ks = 0; ks < 16; ++ks) {
            s16x8 a = *(const s16x8*)(arow + ks * 32);
            acc = __builtin_amdgcn_mfma_f32_16x16x32_bf16(a, bf[ks], acc, 0, 0, 0);
        }

        // epilogue: sigmoid(mask * score / sqrt(32)) -> w0f
        // C/D layout: col = lane&15, row = quad*4 + reg
        #pragma unroll
        for (int r = 0; r < 4; ++r) {
            int rowL = rt * 16 + quad * 4 + r;
            w0f[rowL * WST + ct * 16 + m] =
                sigmoidf_(mskAll[t * 32 + rowL] * acc[r] * INV_SCALE);
        }
        barrier_lds();                                  // (2) w0f ready

        // ---- hidden layer + evaluator fused, all 256 threads busy ----
        #pragma unroll
        for (int tt = 0; tt < 4; ++tt) {
            const int row = slot + 8 * tt;
            const float4* wr = (const float4*)(w0f + row * WST); // broadcast reads
            float s = 0.f;
            #pragma unroll
            for (int i = 0; i < 8; ++i) {
                float4 w4 = wr[i];
                s = fmaf(w4.x, hds[(4 * i + 0) * 32 + k], s);   // conflict-free LDS
                s = fmaf(w4.y, hds[(4 * i + 1) * 32 + k], s);
                s = fmaf(w4.z, hds[(4 * i + 2) * 32 + k], s);
                s = fmaf(w4.w, hds[(4 * i + 3) * 32 + k], s);
            }
            float val = sigmoidf_(s * INV_SCALE) * evk;   // w1[row][k] * ev[k]
            #pragma unroll
            for (int o = 1; o < 32; o <<= 1)              // sum over k (32-lane group)
                val += __shfl_xor(val, o);
            if (k == 0) {
                float v2 = sigmoidf_(val * INV_SCALE);    // in (0,1): exp safe
                float e  = __expf(v2);
                es[row] = e;
                cs[row] = mskAll[t * 32 + row] * e;
            }
        }
        barrier_lds();                                  // (3) cs/es ready

        // ---- tile (Z, DM) partial: wave 0 only ----
        if (tid < 64) {
            float z = 0.f, dm = 0.f;
            if (tid < 32) { z = es[tid]; dm = cs[tid]; }
            #pragma unroll
            for (int o = 32; o > 0; o >>= 1) {
                z  += __shfl_down(z, o);
                dm += __shfl_down(dm, o);
            }
            if (tid == 0) zdm[tile] = make_float2(z, dm);
        }

        // ---- numerator partial: thread owns d = {2*tid, 2*tid+1} ----
        float a0 = 0.f, a1 = 0.f;
        #pragma unroll 8
        for (int row = 0; row < 32; ++row) {
            unsigned u = *(const unsigned*)(xs + row * XST + 2 * tid); // conflict-free
            float x0 = __uint_as_float(u << 16);           // element 2*tid
            float x1 = __uint_as_float(u & 0xffff0000u);   // element 2*tid+1
            float c = cs[row];                              // broadcast
            a0 = fmaf(c, x0, a0);
            a1 = fmaf(c, x1, a1);
        }
        ((float2*)(partial + (size_t)tile * 512))[tid] = make_float2(a0, a1);

        barrier_lds();                                  // (4) xs reads done
    }
}

// ---- reduce 64 partials per b, normalize, write out ----
// grid = 32 batches x 8 column-chunks = 256 blocks (all CUs busy).
__global__ __launch_bounds__(256) void kReduce(
        const float* __restrict__ partial, const float2* __restrict__ zdm,
        float* __restrict__ out) {
    const int b = blockIdx.x >> 3, chunk = blockIdx.x & 7;
    const int tid = threadIdx.x;
    const int c  = tid & 31;             // column within chunk
    const int g  = tid >> 5;             // tile-group 0..7
    const int d2 = chunk * 32 + c;       // float2 column 0..255
    __shared__ float sInv;
    __shared__ float2 red[7][32];

    if (tid < 64) {                      // redundant per block: 512 B from L2
        float2 p = zdm[b * 64 + tid];
        float z = p.x, dm = p.y;
        #pragma unroll
        for (int o = 32; o > 0; o >>= 1) {
            z  += __shfl_down(z, o);
            dm += __shfl_down(dm, o);
        }
        if (tid == 0) sInv = 1.0f / (dm + 1e-12f * z);
    }

    const float2* pp = (const float2*)partial + (size_t)b * 64 * 256 + d2;
    float2 v[8];
    #pragma unroll
    for (int j = 0; j < 8; ++j)                       // 8 loads in flight
        v[j] = pp[(size_t)(g * 8 + j) * 256];
    float a = 0.f, cc = 0.f;
    #pragma unroll
    for (int j = 0; j < 8; ++j) { a += v[j].x; cc += v[j].y; }

    if (g) red[g - 1][c] = make_float2(a, cc);
    __syncthreads();
    if (g == 0) {
        #pragma unroll
        for (int q = 0; q < 7; ++q) { a += red[q][c].x; cc += red[q][c].y; }
        const float inv = sInv;
        ((float2*)out)[b * 256 + d2] = make_float2(a * inv, cc * inv);
    }
}

extern "C" void kernel_launch(void* const* d_in, const int* in_sizes, int n_in,
                              void* d_out, int out_size, void* d_ws, size_t ws_size,
                              hipStream_t stream) {
    const float* inp  = (const float*)d_in[0];
    const int*   mask = (const int*)d_in[1];
    const float* proj = (const float*)d_in[2];
    const float* hid  = (const float*)d_in[3];   // [1][32][32]
    const float* ev   = (const float*)d_in[4];   // [32]
    float* out = (float*)d_out;

    unsigned short* PTbf = (unsigned short*)d_ws;
    float2* zdm     = (float2*)((char*)d_ws + 32768);
    float*  partial = (float*)((char*)d_ws + 49152);

    kTransposeBf<<<64, 256, 0, stream>>>(proj, PTbf);
    kFused      <<<GRID_, 256, 0, stream>>>(inp, mask, PTbf, hid, ev, partial, zdm);
    kReduce     <<<B_ * 8, 256, 0, stream>>>(partial, zdm, out);
}

// Round 7
// 207.338 us; speedup vs baseline: 1.2532x; 1.0091x over previous
//
#include <hip/hip_runtime.h>

#define B_   32
#define S_   2048
#define D_   512
#define H_   32
#define BS_  (B_*S_)
#define NTILE_ (BS_/32)          // 2048 tiles of 32 rows
#define TPB_   4                 // tiles per block (pipelined)
#define GRID_  (NTILE_/TPB_)     // 512 blocks = 2 per CU
#define INV_SCALE 0.17677669529663689f   // 1/sqrt(32)

// workspace layout (bytes):
// [0, 32768):            (unused — former PTbf region)
// [32768, 49152):        zdm     float2[2048]      per-tile (Z, DM) partials
// [49152, 4243456):      partial float[2048][512]  per-tile numerator partials

typedef short  s16x8 __attribute__((ext_vector_type(8)));
typedef float  f32x4 __attribute__((ext_vector_type(4)));

__device__ __forceinline__ float sigmoidf_(float x) {
    return 1.0f / (1.0f + __expf(-x));
}

// LDS-ordering barrier that does NOT drain vmcnt: register-destined global
// prefetch loads stay in flight across it; the compiler's dataflow inserts
// incremental vmcnt(N) waits at first use of each prefetched value.
__device__ __forceinline__ void barrier_lds() {
    asm volatile("s_waitcnt lgkmcnt(0)" ::: "memory");
    __builtin_amdgcn_s_barrier();
    asm volatile("" ::: "memory");
}

// ---- fused scores + unnormalized weighted partial sum ----
#define XST 520                               // bf16 row stride in LDS (512 + 8 pad)
#define WST 36                                // w0f row stride (floats), 16B rows

// __launch_bounds__(256,2): VGPR cap 256. The kernel holds ~170 live regs
// (tmp[16]=64, bf[16]=64, working ~40). R5 showed that forcing 3 waves/EU
// (cap 170 -> allocator chose 84) spills tmp to scratch: WRITE_SIZE blew up
// 4.3MB -> 82MB and kFused ran 119us at 0.7% MfmaUtil. Do not raise this.
__global__ __launch_bounds__(256, 2) void kFused(
        const float* __restrict__ inp, const int* __restrict__ mask,
        const float* __restrict__ proj, const float* __restrict__ hd,
        const float* __restrict__ ev,
        float* __restrict__ partial, float2* __restrict__ zdm) {
    __shared__ __align__(16) unsigned short xs[32 * XST];   // 33280 B
    __shared__ __align__(16) float w0f[32 * WST];           // 4608 B
    __shared__ __align__(16) float hds[32 * 32];            // 4096 B hidden matrix
    __shared__ float cs[32];                  // m * exp(v)
    __shared__ float es[32];                  // exp(v)
    __shared__ float mskAll[TPB_ * 32];       // masks for all 4 tiles

    const int tid = threadIdx.x;
    const int wave = tid >> 6, lane = tid & 63;
    const int rt = wave & 1, ct = wave >> 1;
    const int m = lane & 15, quad = lane >> 4;
    const int tile0 = blockIdx.x * TPB_;

    // ---- issue tile-0 loads FIRST so the HBM stream starts immediately ----
    float4 tmp[16];                                    // 64 VGPR
    {
        const float4* g = (const float4*)inp + (size_t)tile0 * 4096;
        #pragma unroll
        for (int i = 0; i < 16; ++i)
            tmp[i] = g[i * 256 + tid];                 // flat index == row*128 + kq
    }

    // ---- gather B fragments directly from proj (64 KiB, L2/L3-hot) ----
    // bf[ks][e] must equal bf16(proj[(quad*8 + ks*32 + e)][ct*16 + m]),
    // identical values to the former PTbf transpose kernel. Gather cost
    // (128 strided dword loads/lane, once per block) hides under the
    // tile-0 prefetch that is already in flight.
    s16x8 bf[16];                                      // 64 VGPR (B fragments)
    {
        const int col = ct * 16 + m;
        #pragma unroll
        for (int ks = 0; ks < 16; ++ks) {
            float f0 = proj[(size_t)(quad * 8 + ks * 32 + 0) * 32 + col];
            float f1 = proj[(size_t)(quad * 8 + ks * 32 + 1) * 32 + col];
            float f2 = proj[(size_t)(quad * 8 + ks * 32 + 2) * 32 + col];
            float f3 = proj[(size_t)(quad * 8 + ks * 32 + 3) * 32 + col];
            float f4 = proj[(size_t)(quad * 8 + ks * 32 + 4) * 32 + col];
            float f5 = proj[(size_t)(quad * 8 + ks * 32 + 5) * 32 + col];
            float f6 = proj[(size_t)(quad * 8 + ks * 32 + 6) * 32 + col];
            float f7 = proj[(size_t)(quad * 8 + ks * 32 + 7) * 32 + col];
            union { unsigned u[4]; s16x8 v; } bb;
            asm("v_cvt_pk_bf16_f32 %0, %1, %2" : "=v"(bb.u[0]) : "v"(f0), "v"(f1));
            asm("v_cvt_pk_bf16_f32 %0, %1, %2" : "=v"(bb.u[1]) : "v"(f2), "v"(f3));
            asm("v_cvt_pk_bf16_f32 %0, %1, %2" : "=v"(bb.u[2]) : "v"(f4), "v"(f5));
            asm("v_cvt_pk_bf16_f32 %0, %1, %2" : "=v"(bb.u[3]) : "v"(f6), "v"(f7));
            bf[ks] = bb.v;
        }
    }

    const int k = tid & 31, slot = tid >> 5;
    ((float4*)hds)[tid] = ((const float4*)hd)[tid];    // 4 KiB stage (exactly 256 f4)
    const float evk = ev[k];
    if (tid < TPB_ * 32)
        mskAll[tid] = (mask[tile0 * 32 + tid] != 0) ? 1.0f : 0.0f;

    for (int t = 0; t < TPB_; ++t) {
        const int tile = tile0 + t;

        // ---- stage tile t: bf16 convert + LDS write (incremental vmcnt waits) ----
        #pragma unroll
        for (int i = 0; i < 16; ++i) {
            int fi = i * 256 + tid;
            int row = fi >> 7, kq = fi & 127;
            unsigned p0, p1;                  // HW RNE pack
            asm("v_cvt_pk_bf16_f32 %0, %1, %2" : "=v"(p0) : "v"(tmp[i].x), "v"(tmp[i].y));
            asm("v_cvt_pk_bf16_f32 %0, %1, %2" : "=v"(p1) : "v"(tmp[i].z), "v"(tmp[i].w));
            uint2 u; u.x = p0; u.y = p1;
            *(uint2*)(xs + row * XST + kq * 4) = u;
        }

        // ---- prefetch tile t+1 BEFORE the barrier (tmp is dead after cvt):
        // loads start during other waves' cvt and stay in flight across all
        // tail barriers (barrier_lds never drains vmcnt).
        if (t + 1 < TPB_) {
            const float4* g2 = (const float4*)inp + (size_t)(tile + 1) * 4096;
            #pragma unroll
            for (int i = 0; i < 16; ++i)
                tmp[i] = g2[i * 256 + tid];
        }
        barrier_lds();                                  // (1) xs/hds/msk ready

        // ---- MFMA: each wave one 16x16 tile (rowtile rt, coltile ct) ----
        const unsigned short* arow = xs + (rt * 16 + m) * XST + quad * 8;
        f32x4 acc = {0.f, 0.f, 0.f, 0.f};
        #pragma unroll
        for (int ks = 0; ks < 16; ++ks) {
            s16x8 a = *(const s16x8*)(arow + ks * 32);
            acc = __builtin_amdgcn_mfma_f32_16x16x32_bf16(a, bf[ks], acc, 0, 0, 0);
        }

        // epilogue: sigmoid(mask * score / sqrt(32)) -> w0f
        // C/D layout: col = lane&15, row = quad*4 + reg
        #pragma unroll
        for (int r = 0; r < 4; ++r) {
            int rowL = rt * 16 + quad * 4 + r;
            w0f[rowL * WST + ct * 16 + m] =
                sigmoidf_(mskAll[t * 32 + rowL] * acc[r] * INV_SCALE);
        }
        barrier_lds();                                  // (2) w0f ready

        // ---- hidden layer + evaluator fused, all 256 threads busy ----
        #pragma unroll
        for (int tt = 0; tt < 4; ++tt) {
            const int row = slot + 8 * tt;
            const float4* wr = (const float4*)(w0f + row * WST); // broadcast reads
            float s = 0.f;
            #pragma unroll
            for (int i = 0; i < 8; ++i) {
                float4 w4 = wr[i];
                s = fmaf(w4.x, hds[(4 * i + 0) * 32 + k], s);   // conflict-free LDS
                s = fmaf(w4.y, hds[(4 * i + 1) * 32 + k], s);
                s = fmaf(w4.z, hds[(4 * i + 2) * 32 + k], s);
                s = fmaf(w4.w, hds[(4 * i + 3) * 32 + k], s);
            }
            float val = sigmoidf_(s * INV_SCALE) * evk;   // w1[row][k] * ev[k]
            #pragma unroll
            for (int o = 1; o < 32; o <<= 1)              // sum over k (32-lane group)
                val += __shfl_xor(val, o);
            if (k == 0) {
                float v2 = sigmoidf_(val * INV_SCALE);    // in (0,1): exp safe
                float e  = __expf(v2);
                es[row] = e;
                cs[row] = mskAll[t * 32 + row] * e;
            }
        }
        barrier_lds();                                  // (3) cs/es ready

        // ---- tile (Z, DM) partial: wave 0 only ----
        if (tid < 64) {
            float z = 0.f, dm = 0.f;
            if (tid < 32) { z = es[tid]; dm = cs[tid]; }
            #pragma unroll
            for (int o = 32; o > 0; o >>= 1) {
                z  += __shfl_down(z, o);
                dm += __shfl_down(dm, o);
            }
            if (tid == 0) zdm[tile] = make_float2(z, dm);
        }

        // ---- numerator partial: thread owns d = {2*tid, 2*tid+1} ----
        float a0 = 0.f, a1 = 0.f;
        #pragma unroll 8
        for (int row = 0; row < 32; ++row) {
            unsigned u = *(const unsigned*)(xs + row * XST + 2 * tid); // conflict-free
            float x0 = __uint_as_float(u << 16);           // element 2*tid
            float x1 = __uint_as_float(u & 0xffff0000u);   // element 2*tid+1
            float c = cs[row];                              // broadcast
            a0 = fmaf(c, x0, a0);
            a1 = fmaf(c, x1, a1);
        }
        ((float2*)(partial + (size_t)tile * 512))[tid] = make_float2(a0, a1);

        barrier_lds();                                  // (4) xs reads done
    }
}

// ---- reduce 64 partials per b, normalize, write out ----
// 1024 threads: 4 groups of 256; each group sums 16 tiles. Every load is a
// contiguous 2 KiB per 256-thread group (coalesced), 16 loads in flight.
__global__ __launch_bounds__(1024) void kReduce(
        const float* __restrict__ partial, const float2* __restrict__ zdm,
        float* __restrict__ out) {
    const int b = blockIdx.x, tid = threadIdx.x;
    const int d2 = tid & 255;            // float2 column (2 d per thread)
    const int g  = tid >> 8;             // tile-group 0..3
    __shared__ float sInv;
    __shared__ float2 red[3][256];

    if (tid < 64) {
        float2 p = zdm[b * 64 + tid];
        float z = p.x, dm = p.y;
        #pragma unroll
        for (int o = 32; o > 0; o >>= 1) {
            z  += __shfl_down(z, o);
            dm += __shfl_down(dm, o);
        }
        if (tid == 0) sInv = 1.0f / (dm + 1e-12f * z);
    }

    const float2* pp = (const float2*)partial + (size_t)b * 64 * 256 + d2;
    float2 v[16];
    #pragma unroll
    for (int j = 0; j < 16; ++j)                     // 16 loads in flight
        v[j] = pp[(size_t)(g * 16 + j) * 256];
    float a = 0.f, c = 0.f;
    #pragma unroll
    for (int j = 0; j < 16; ++j) { a += v[j].x; c += v[j].y; }

    if (g) red[g - 1][d2] = make_float2(a, c);
    __syncthreads();
    if (g == 0) {
        #pragma unroll
        for (int q = 0; q < 3; ++q) { a += red[q][d2].x; c += red[q][d2].y; }
        const float inv = sInv;
        ((float2*)out)[b * 256 + d2] = make_float2(a * inv, c * inv);
    }
}

extern "C" void kernel_launch(void* const* d_in, const int* in_sizes, int n_in,
                              void* d_out, int out_size, void* d_ws, size_t ws_size,
                              hipStream_t stream) {
    const float* inp  = (const float*)d_in[0];
    const int*   mask = (const int*)d_in[1];
    const float* proj = (const float*)d_in[2];
    const float* hid  = (const float*)d_in[3];   // [1][32][32]
    const float* ev   = (const float*)d_in[4];   // [32]
    float* out = (float*)d_out;

    float2* zdm     = (float2*)((char*)d_ws + 32768);
    float*  partial = (float*)((char*)d_ws + 49152);

    kFused <<<GRID_, 256, 0, stream>>>(inp, mask, proj, hid, ev, partial, zdm);
    kReduce<<<B_, 1024, 0, stream>>>(partial, zdm, out);
}

// Round 8
// 204.609 us; speedup vs baseline: 1.2699x; 1.0133x over previous
//
#include <hip/hip_runtime.h>

#define B_   32
#define S_   2048
#define D_   512
#define H_   32
#define BS_  (B_*S_)
#define NTILE_ (BS_/32)          // 2048 tiles of 32 rows
#define TPB_   4                 // tiles per block (pipelined)
#define GRID_  (NTILE_/TPB_)     // 512 blocks = 2 per CU
#define INV_SCALE 0.17677669529663689f   // 1/sqrt(32)

// workspace layout (bytes):
// [0, 32768):            (unused)
// [32768, 49152):        zdm     float2[2048]      per-tile (Z, DM) partials
// [49152, 4243456):      partial float[2048][512]  per-tile numerator partials

typedef short  s16x8 __attribute__((ext_vector_type(8)));
typedef float  f32x4 __attribute__((ext_vector_type(4)));

__device__ __forceinline__ float sigmoidf_(float x) {
    return 1.0f / (1.0f + __expf(-x));
}

// LDS-ordering barrier that does NOT drain vmcnt: register-destined global
// prefetch loads stay in flight across it; the compiler's dataflow inserts
// incremental vmcnt(N) waits at first use of each prefetched value. The
// "memory" clobbers also pin each prefetch group between its barriers, so
// load-issue points stay spread across the tile's phases.
__device__ __forceinline__ void barrier_lds() {
    asm volatile("s_waitcnt lgkmcnt(0)" ::: "memory");
    __builtin_amdgcn_s_barrier();
    asm volatile("" ::: "memory");
}

// ---- fused scores + unnormalized weighted partial sum ----
#define XST 520                               // bf16 row stride in LDS (512 + 8 pad)
#define WST 36                                // w0f row stride (floats), 16B rows

// __launch_bounds__(256,2): VGPR cap 256. The kernel holds ~170 live regs
// (tmp[16]=64, bf[16]=64, working ~40). R5 showed that forcing 3 waves/EU
// spills tmp to scratch (WRITE_SIZE 4.3MB->82MB, kFused 119us). Keep at 2.
__global__ __launch_bounds__(256, 2) void kFused(
        const float* __restrict__ inp, const int* __restrict__ mask,
        const float* __restrict__ proj, const float* __restrict__ hd,
        const float* __restrict__ ev,
        float* __restrict__ partial, float2* __restrict__ zdm) {
    __shared__ __align__(16) unsigned short xs[32 * XST];   // 33280 B
    __shared__ __align__(16) float w0f[32 * WST];           // 4608 B
    __shared__ __align__(16) float hds[32 * 32];            // 4096 B hidden matrix
    __shared__ float cs[32];                  // m * exp(v)
    __shared__ float es[32];                  // exp(v)
    __shared__ float mskAll[TPB_ * 32];       // masks for all 4 tiles

    const int tid = threadIdx.x;
    const int wave = tid >> 6, lane = tid & 63;
    const int rt = wave & 1, ct = wave >> 1;
    const int m = lane & 15, quad = lane >> 4;
    const int tile0 = blockIdx.x * TPB_;

    // ---- issue tile-0 loads FIRST so the HBM stream starts immediately ----
    float4 tmp[16];                                    // 64 VGPR
    {
        const float4* g = (const float4*)inp + (size_t)tile0 * 4096;
        #pragma unroll
        for (int i = 0; i < 16; ++i)
            tmp[i] = g[i * 256 + tid];                 // flat index == row*128 + kq
    }

    // ---- gather B fragments directly from proj (64 KiB, cache-hot) ----
    // bf[ks][e] = bf16(proj[(quad*8 + ks*32 + e)][ct*16 + m]); once per block,
    // hides under the tile-0 prefetch already in flight.
    s16x8 bf[16];                                      // 64 VGPR (B fragments)
    {
        const int col = ct * 16 + m;
        #pragma unroll
        for (int ks = 0; ks < 16; ++ks) {
            float f0 = proj[(size_t)(quad * 8 + ks * 32 + 0) * 32 + col];
            float f1 = proj[(size_t)(quad * 8 + ks * 32 + 1) * 32 + col];
            float f2 = proj[(size_t)(quad * 8 + ks * 32 + 2) * 32 + col];
            float f3 = proj[(size_t)(quad * 8 + ks * 32 + 3) * 32 + col];
            float f4 = proj[(size_t)(quad * 8 + ks * 32 + 4) * 32 + col];
            float f5 = proj[(size_t)(quad * 8 + ks * 32 + 5) * 32 + col];
            float f6 = proj[(size_t)(quad * 8 + ks * 32 + 6) * 32 + col];
            float f7 = proj[(size_t)(quad * 8 + ks * 32 + 7) * 32 + col];
            union { unsigned u[4]; s16x8 v; } bb;
            asm("v_cvt_pk_bf16_f32 %0, %1, %2" : "=v"(bb.u[0]) : "v"(f0), "v"(f1));
            asm("v_cvt_pk_bf16_f32 %0, %1, %2" : "=v"(bb.u[1]) : "v"(f2), "v"(f3));
            asm("v_cvt_pk_bf16_f32 %0, %1, %2" : "=v"(bb.u[2]) : "v"(f4), "v"(f5));
            asm("v_cvt_pk_bf16_f32 %0, %1, %2" : "=v"(bb.u[3]) : "v"(f6), "v"(f7));
            bf[ks] = bb.v;
        }
    }

    const int k = tid & 31, slot = tid >> 5;
    ((float4*)hds)[tid] = ((const float4*)hd)[tid];    // 4 KiB stage (exactly 256 f4)
    const float evk = ev[k];
    if (tid < TPB_ * 32)
        mskAll[tid] = (mask[tile0 * 32 + tid] != 0) ? 1.0f : 0.0f;

    for (int t = 0; t < TPB_; ++t) {
        const int tile = tile0 + t;
        const float4* g2 = (const float4*)inp + (size_t)(tile + 1) * 4096;
        const bool pf = (t + 1 < TPB_);

        // ---- stage tile t: bf16 convert + LDS write (incremental vmcnt waits) ----
        #pragma unroll
        for (int i = 0; i < 16; ++i) {
            int fi = i * 256 + tid;
            int row = fi >> 7, kq = fi & 127;
            unsigned p0, p1;                  // HW RNE pack
            asm("v_cvt_pk_bf16_f32 %0, %1, %2" : "=v"(p0) : "v"(tmp[i].x), "v"(tmp[i].y));
            asm("v_cvt_pk_bf16_f32 %0, %1, %2" : "=v"(p1) : "v"(tmp[i].z), "v"(tmp[i].w));
            uint2 u; u.x = p0; u.y = p1;
            *(uint2*)(xs + row * XST + kq * 4) = u;
        }

        // ---- prefetch group A (6/16): issued during other waves' cvt; the
        // remaining groups are issued after later barriers so this wave keeps
        // VMEM issue alive through every phase of the tile (anti-convoy).
        if (pf) {
            #pragma unroll
            for (int i = 0; i < 6; ++i)
                tmp[i] = g2[i * 256 + tid];
        }
        barrier_lds();                                  // (1) xs/hds/msk ready

        // ---- MFMA: each wave one 16x16 tile (rowtile rt, coltile ct) ----
        const unsigned short* arow = xs + (rt * 16 + m) * XST + quad * 8;
        f32x4 acc = {0.f, 0.f, 0.f, 0.f};
        #pragma unroll
        for (int ks = 0; ks < 16; ++ks) {
            s16x8 a = *(const s16x8*)(arow + ks * 32);
            acc = __builtin_amdgcn_mfma_f32_16x16x32_bf16(a, bf[ks], acc, 0, 0, 0);
        }

        // epilogue: sigmoid(mask * score / sqrt(32)) -> w0f
        // C/D layout: col = lane&15, row = quad*4 + reg
        #pragma unroll
        for (int r = 0; r < 4; ++r) {
            int rowL = rt * 16 + quad * 4 + r;
            w0f[rowL * WST + ct * 16 + m] =
                sigmoidf_(mskAll[t * 32 + rowL] * acc[r] * INV_SCALE);
        }
        barrier_lds();                                  // (2) w0f ready

        // ---- prefetch group B (5/16) ----
        if (pf) {
            #pragma unroll
            for (int i = 6; i < 11; ++i)
                tmp[i] = g2[i * 256 + tid];
        }

        // ---- hidden layer + evaluator fused, all 256 threads busy ----
        #pragma unroll
        for (int tt = 0; tt < 4; ++tt) {
            const int row = slot + 8 * tt;
            const float4* wr = (const float4*)(w0f + row * WST); // broadcast reads
            float s = 0.f;
            #pragma unroll
            for (int i = 0; i < 8; ++i) {
                float4 w4 = wr[i];
                s = fmaf(w4.x, hds[(4 * i + 0) * 32 + k], s);   // conflict-free LDS
                s = fmaf(w4.y, hds[(4 * i + 1) * 32 + k], s);
                s = fmaf(w4.z, hds[(4 * i + 2) * 32 + k], s);
                s = fmaf(w4.w, hds[(4 * i + 3) * 32 + k], s);
            }
            float val = sigmoidf_(s * INV_SCALE) * evk;   // w1[row][k] * ev[k]
            #pragma unroll
            for (int o = 1; o < 32; o <<= 1)              // sum over k (32-lane group)
                val += __shfl_xor(val, o);
            if (k == 0) {
                float v2 = sigmoidf_(val * INV_SCALE);    // in (0,1): exp safe
                float e  = __expf(v2);
                es[row] = e;
                cs[row] = mskAll[t * 32 + row] * e;
            }
        }
        barrier_lds();                                  // (3) cs/es ready

        // ---- prefetch group C (5/16) ----
        if (pf) {
            #pragma unroll
            for (int i = 11; i < 16; ++i)
                tmp[i] = g2[i * 256 + tid];
        }

        // ---- tile (Z, DM) partial: wave 0 only ----
        if (tid < 64) {
            float z = 0.f, dm = 0.f;
            if (tid < 32) { z = es[tid]; dm = cs[tid]; }
            #pragma unroll
            for (int o = 32; o > 0; o >>= 1) {
                z  += __shfl_down(z, o);
                dm += __shfl_down(dm, o);
            }
            if (tid == 0) zdm[tile] = make_float2(z, dm);
        }

        // ---- numerator partial: thread owns d = {2*tid, 2*tid+1} ----
        float a0 = 0.f, a1 = 0.f;
        #pragma unroll 8
        for (int row = 0; row < 32; ++row) {
            unsigned u = *(const unsigned*)(xs + row * XST + 2 * tid); // conflict-free
            float x0 = __uint_as_float(u << 16);           // element 2*tid
            float x1 = __uint_as_float(u & 0xffff0000u);   // element 2*tid+1
            float c = cs[row];                              // broadcast
            a0 = fmaf(c, x0, a0);
            a1 = fmaf(c, x1, a1);
        }
        ((float2*)(partial + (size_t)tile * 512))[tid] = make_float2(a0, a1);

        barrier_lds();                                  // (4) xs reads done
    }
}

// ---- reduce 64 partials per b, normalize, write out ----
// 1024 threads: 4 groups of 256; each group sums 16 tiles. Every load is a
// contiguous 2 KiB per 256-thread group (coalesced), 16 loads in flight.
__global__ __launch_bounds__(1024) void kReduce(
        const float* __restrict__ partial, const float2* __restrict__ zdm,
        float* __restrict__ out) {
    const int b = blockIdx.x, tid = threadIdx.x;
    const int d2 = tid & 255;            // float2 column (2 d per thread)
    const int g  = tid >> 8;             // tile-group 0..3
    __shared__ float sInv;
    __shared__ float2 red[3][256];

    if (tid < 64) {
        float2 p = zdm[b * 64 + tid];
        float z = p.x, dm = p.y;
        #pragma unroll
        for (int o = 32; o > 0; o >>= 1) {
            z  += __shfl_down(z, o);
            dm += __shfl_down(dm, o);
        }
        if (tid == 0) sInv = 1.0f / (dm + 1e-12f * z);
    }

    const float2* pp = (const float2*)partial + (size_t)b * 64 * 256 + d2;
    float2 v[16];
    #pragma unroll
    for (int j = 0; j < 16; ++j)                     // 16 loads in flight
        v[j] = pp[(size_t)(g * 16 + j) * 256];
    float a = 0.f, c = 0.f;
    #pragma unroll
    for (int j = 0; j < 16; ++j) { a += v[j].x; c += v[j].y; }

    if (g) red[g - 1][d2] = make_float2(a, c);
    __syncthreads();
    if (g == 0) {
        #pragma unroll
        for (int q = 0; q < 3; ++q) { a += red[q][d2].x; c += red[q][d2].y; }
        const float inv = sInv;
        ((float2*)out)[b * 256 + d2] = make_float2(a * inv, c * inv);
    }
}

extern "C" void kernel_launch(void* const* d_in, const int* in_sizes, int n_in,
                              void* d_out, int out_size, void* d_ws, size_t ws_size,
                              hipStream_t stream) {
    const float* inp  = (const float*)d_in[0];
    const int*   mask = (const int*)d_in[1];
    const float* proj = (const float*)d_in[2];
    const float* hid  = (const float*)d_in[3];   // [1][32][32]
    const float* ev   = (const float*)d_in[4];   // [32]
    float* out = (float*)d_out;

    float2* zdm     = (float2*)((char*)d_ws + 32768);
    float*  partial = (float*)((char*)d_ws + 49152);

    kFused <<<GRID_, 256, 0, stream>>>(inp, mask, proj, hid, ev, partial, zdm);
    kReduce<<<B_, 1024, 0, stream>>>(partial, zdm, out);
}